// Round 3
// baseline (127.734 us; speedup 1.0000x reference)
//
#include <hip/hip_runtime.h>
#include <hip/hip_bf16.h>
#include <stdint.h>

// out[i][j] = dot(x[i], y[j]) / max(|x[i]|*|y[j]|, 1e-8) / 0.05
// x,y: [4096,1024] f32; out: [4096,4096] f32
#define MDIM 4096
#define NDIM 4096
#define KDIM 1024
#define TEMP_INV 20.0f
#define BM 256
#define BN 128
#define BK 64

typedef __bf16 bf16x8 __attribute__((ext_vector_type(8)));
typedef float f32x16 __attribute__((ext_vector_type(16)));

typedef __attribute__((address_space(3))) void lds_void_t;
typedef __attribute__((address_space(1))) void glb_void_t;

__device__ __forceinline__ void async_copy16(const void* g, void* l) {
    __builtin_amdgcn_global_load_lds((glb_void_t*)(uintptr_t)g,
                                     (lds_void_t*)(uint32_t)(uintptr_t)l,
                                     16, 0, 0);
}

__device__ __forceinline__ unsigned short f32_to_bf16_rne(float f) {
    union { float f; uint32_t u; } v;
    v.f = f;
    uint32_t u = v.u;
    return (unsigned short)((u + 0x7FFFu + ((u >> 16) & 1u)) >> 16);
}

// Wave-per-row prep: no LDS, no __syncthreads. Block = 4 waves = 4 rows.
__global__ __launch_bounds__(256) void prep_kernel(const float* __restrict__ x,
                                                   const float* __restrict__ y,
                                                   unsigned short* __restrict__ xb,
                                                   unsigned short* __restrict__ yb,
                                                   float* __restrict__ rnx,
                                                   float* __restrict__ rny) {
    const int wv = threadIdx.x >> 6;
    const int lane = threadIdx.x & 63;
    const int row = blockIdx.x * 4 + wv;
    const float* src = blockIdx.y ? y : x;
    unsigned short* dst = blockIdx.y ? yb : xb;
    float* rn = blockIdx.y ? rny : rnx;

    const float4* s4 = (const float4*)(src + (size_t)row * KDIM);
    ushort4* d4 = (ushort4*)(dst + (size_t)row * KDIM);

    float ss = 0.0f;
#pragma unroll
    for (int it = 0; it < 4; ++it) {
        float4 v = s4[lane + it * 64];
        ss += v.x * v.x + v.y * v.y + v.z * v.z + v.w * v.w;
        ushort4 b;
        b.x = f32_to_bf16_rne(v.x);
        b.y = f32_to_bf16_rne(v.y);
        b.z = f32_to_bf16_rne(v.z);
        b.w = f32_to_bf16_rne(v.w);
        d4[lane + it * 64] = b;
    }
#pragma unroll
    for (int off = 32; off > 0; off >>= 1) ss += __shfl_down(ss, off);
    if (lane == 0) rn[row] = 1.0f / fmaxf(sqrtf(ss), 1e-8f);
}

// 256x128 block tile, BK=64. 4 waves in 2x2; each wave owns a 128x64 subtile
// computed as a 4x2 grid of 32x32x16 MFMAs (6 LDS reads feed 8 MFMAs).
// LDS rows are 128 B = 8 chunks of 16 B; chunk slot c' holds global chunk
// c' ^ (row&7) (XOR swizzle keeps ds_read_b128 conflict-free while the
// global_load_lds DMA stays lane-contiguous).
__global__ __launch_bounds__(256, 2) void gemm_cos_kernel(const unsigned short* __restrict__ Xb,
                                                          const unsigned short* __restrict__ Yb,
                                                          const float* __restrict__ rnx,
                                                          const float* __restrict__ rny,
                                                          float* __restrict__ out) {
    __shared__ __bf16 As[BM * BK];  // 32 KB
    __shared__ __bf16 Bs[BN * BK];  // 16 KB

    const int tid = threadIdx.x;
    const int bm = blockIdx.y;
    const int bn = blockIdx.x;

    // Staging: thread t covers segment-row (t>>3) within a 32-row segment,
    // chunk slot (t&7); the global chunk it fetches is (t&7) ^ (row&7).
    const int srow = tid >> 3;
    const int gchunk = (tid & 7) ^ (srow & 7);
    const unsigned short* gA = Xb + (size_t)(bm * BM + srow) * KDIM + gchunk * 8;
    const unsigned short* gB = Yb + (size_t)(bn * BN + srow) * KDIM + gchunk * 8;
    __bf16* lA = As + tid * 8;  // + seg*2048 elems (4 KB) per 32-row segment
    __bf16* lB = Bs + tid * 8;

    const int lane = tid & 63;
    const int wv = tid >> 6;
    const int mw = (wv >> 1) * 128;  // wave row origin
    const int nw = (wv & 1) * 64;    // wave col origin
    const int n32 = lane & 31;
    const int half = lane >> 5;
    const int rsw = n32 & 7;

    // Element base offsets (row * BK elems per LDS row).
    int aOff[4], bOff[2];
#pragma unroll
    for (int i = 0; i < 4; ++i) aOff[i] = (mw + i * 32 + n32) * BK;
#pragma unroll
    for (int j = 0; j < 2; ++j) bOff[j] = (nw + j * 32 + n32) * BK;

    f32x16 acc[4][2] = {};

    for (int kt = 0; kt < KDIM; kt += BK) {
        __syncthreads();
#pragma unroll
        for (int seg = 0; seg < 8; ++seg)
            async_copy16(gA + kt + (size_t)seg * 32 * KDIM, lA + seg * 2048);
#pragma unroll
        for (int seg = 0; seg < 4; ++seg)
            async_copy16(gB + kt + (size_t)seg * 32 * KDIM, lB + seg * 2048);
        __syncthreads();

#pragma unroll
        for (int s = 0; s < 4; ++s) {
            const int cp = ((2 * s + half) ^ rsw) * 8;
            bf16x8 b0 = *(const bf16x8*)(Bs + bOff[0] + cp);
            bf16x8 b1 = *(const bf16x8*)(Bs + bOff[1] + cp);
#pragma unroll
            for (int i = 0; i < 4; ++i) {
                bf16x8 a = *(const bf16x8*)(As + aOff[i] + cp);
                acc[i][0] = __builtin_amdgcn_mfma_f32_32x32x16_bf16(a, b0, acc[i][0], 0, 0, 0);
                acc[i][1] = __builtin_amdgcn_mfma_f32_32x32x16_bf16(a, b1, acc[i][1], 0, 0, 0);
            }
        }
    }

    // C/D layout (m74/m101): col = lane&31, row = (reg&3) + 8*(reg>>2) + 4*(lane>>5).
    const int grb = bm * BM + mw + 4 * half;
    const int gcb = bn * BN + nw + n32;
    const float sy0 = rny[gcb] * TEMP_INV;
    const float sy1 = rny[gcb + 32] * TEMP_INV;

#pragma unroll
    for (int i = 0; i < 4; ++i) {
#pragma unroll
        for (int r = 0; r < 16; ++r) {
            const int ro = (r & 3) + 8 * (r >> 2);
            const int grow = grb + i * 32 + ro;
            const float rx = rnx[grow];
            out[(size_t)grow * NDIM + gcb] = acc[i][0][r] * rx * sy0;
            out[(size_t)grow * NDIM + gcb + 32] = acc[i][1][r] * rx * sy1;
        }
    }
}

extern "C" void kernel_launch(void* const* d_in, const int* in_sizes, int n_in,
                              void* d_out, int out_size, void* d_ws, size_t ws_size,
                              hipStream_t stream) {
    const float* x = (const float*)d_in[0];
    const float* y = (const float*)d_in[1];
    float* out = (float*)d_out;

    char* ws = (char*)d_ws;
    unsigned short* Xb = (unsigned short*)ws;                              // 8 MB
    unsigned short* Yb = (unsigned short*)(ws + (size_t)MDIM * KDIM * 2);  // 8 MB
    float* rnx = (float*)(ws + (size_t)(MDIM + NDIM) * KDIM * 2);
    float* rny = rnx + MDIM;

    prep_kernel<<<dim3(MDIM / 4, 2), 256, 0, stream>>>(x, y, Xb, Yb, rnx, rny);
    gemm_cos_kernel<<<dim3(NDIM / BN, MDIM / BM), 256, 0, stream>>>(Xb, Yb, rnx, rny, out);
}